// Round 6
// baseline (42.781 us; speedup 1.0000x reference)
//
#include <hip/hip_runtime.h>
#include <math.h>

// LogicConv2d, two-kernel form, pipelined main.
//
// prep (1 block): softmax(sel_a), softmax(sel_b), collapse 16-way mix to
//   out = Cab*ab + Ca*a + Cb*b + C0. tab[81][24] in d_ws.
//
// main: 1024 blocks x 2 tiles of 64 batches. Per tile: stage LDS -> compute
//   (3 waves x 27 units, fully unrolled, weights via wave-uniform s_loads)
//   -> writeback. Tile 1's global loads are issued into registers BEFORE
//   tile 0's compute so loads/stores/compute overlap (no chip-wide phase
//   lockstep). Single 20.7 KB LDS tile reused for input and output.

#define NB      131072
#define NUNITS  81
#define BPB     64            // batches per tile
#define THREADS 256
#define NBLK    1024          // blocks; each does 2 tiles
#define REC     24            // floats per unit record
#define CHUNKS  1296          // BPB*81/4 float4 per tile

__global__ __launch_bounds__(256)
void logic_prep_kernel(const float* __restrict__ sa_logits,
                       const float* __restrict__ sb_logits,
                       const float* __restrict__ op_logits,
                       float* __restrict__ tab)
{
    const int tid = threadIdx.x;
    if (tid < 81) {
        const int u = tid;
        float v[9], m = -1e30f;
        #pragma unroll
        for (int i = 0; i < 9; ++i) { v[i] = sa_logits[u * 9 + i]; m = fmaxf(m, v[i]); }
        float s = 0.f;
        #pragma unroll
        for (int i = 0; i < 9; ++i) { v[i] = expf(v[i] - m); s += v[i]; }
        const float r = 1.f / s;
        #pragma unroll
        for (int i = 0; i < 9; ++i) tab[u * REC + i] = v[i] * r;
    } else if (tid < 162) {
        const int u = tid - 81;
        float v[9], m = -1e30f;
        #pragma unroll
        for (int i = 0; i < 9; ++i) { v[i] = sb_logits[u * 9 + i]; m = fmaxf(m, v[i]); }
        float s = 0.f;
        #pragma unroll
        for (int i = 0; i < 9; ++i) { v[i] = expf(v[i] - m); s += v[i]; }
        const float r = 1.f / s;
        #pragma unroll
        for (int i = 0; i < 9; ++i) tab[u * REC + 9 + i] = v[i] * r;
    } else if (tid < 243) {
        const int u = tid - 162;
        float v[16], m = -1e30f;
        #pragma unroll
        for (int i = 0; i < 16; ++i) { v[i] = op_logits[u * 16 + i]; m = fmaxf(m, v[i]); }
        float s = 0.f;
        #pragma unroll
        for (int i = 0; i < 16; ++i) { v[i] = expf(v[i] - m); s += v[i]; }
        const float r = 1.f / s;
        #pragma unroll
        for (int i = 0; i < 16; ++i) v[i] *= r;
        const float cab = v[1] - v[2] - v[4] - 2.f*v[6] - v[7] + v[8] + 2.f*v[9]
                        + v[11] + v[13] - v[14];
        const float ca  = v[2] + v[3] + v[6] + v[7] - v[8] - v[9] - v[12] - v[13];
        const float cb  = v[4] + v[5] + v[6] + v[7] - v[8] - v[9] - v[10] - v[11];
        const float c0  = v[8] + v[9] + v[10] + v[11] + v[12] + v[13] + v[14] + v[15];
        tab[u * REC + 18] = cab;
        tab[u * REC + 19] = ca;
        tab[u * REC + 20] = cb;
        tab[u * REC + 21] = c0;
    }
}

__device__ __forceinline__
void compute_tile(float* __restrict__ s_tile, const float* __restrict__ tab,
                  int lane, int wavei)
{
    if (wavei < 3) {
        float* my = s_tile + lane * 81 + wavei * 27;  // own slice: read == write

        float in[27];
        #pragma unroll
        for (int j = 0; j < 27; ++j) in[j] = my[j];

        const float* __restrict__ wt = tab + wavei * 27 * REC;  // uniform base

        #pragma unroll
        for (int j = 0; j < 27; ++j) {                 // unit u = 27*wavei + j
            const int q = j / 9;
            const float* __restrict__ wr = wt + j * REC;
            float a = 0.f, b = 0.f;
            #pragma unroll
            for (int i = 0; i < 9; ++i) {
                const float xi = in[q * 3 + (i / 3) * 9 + (i % 3)];
                a = fmaf(xi, wr[i],     a);
                b = fmaf(xi, wr[9 + i], b);
            }
            const float ab = a * b;
            my[j] = fmaf(wr[18], ab, fmaf(wr[19], a, fmaf(wr[20], b, wr[21])));
        }
    }
}

__global__ __launch_bounds__(THREADS)
void logic_main_kernel(const float* __restrict__ x,
                       const float* __restrict__ tab,
                       float* __restrict__ out)
{
    __shared__ float s_tile[BPB * 81];    // 20736 B, reused across both tiles

    const int tid   = threadIdx.x;
    const int lane  = tid & 63;
    const int wavei = __builtin_amdgcn_readfirstlane(tid >> 6);
    const int bid   = blockIdx.x;

    const float4* __restrict__ x4   = (const float4*)x;
    float4* __restrict__       out4 = (float4*)out;
    float4* s4 = (float4*)s_tile;

    float4 r[6];

    // ---- prefetch tile A (T = bid) into registers ----
    {
        const float4* g = x4 + (size_t)bid * CHUNKS;
        #pragma unroll
        for (int k = 0; k < 6; ++k) {
            int j = tid + k * THREADS;
            if (j < CHUNKS) r[k] = g[j];
        }
    }

    // ================= tile A =================
    #pragma unroll
    for (int k = 0; k < 6; ++k) {          // regs -> LDS (vmcnt wait auto)
        int j = tid + k * THREADS;
        if (j < CHUNKS) s4[j] = r[k];
    }
    __syncthreads();

    // ---- prefetch tile B (T = bid + NBLK) while computing tile A ----
    {
        const float4* g = x4 + (size_t)(bid + NBLK) * CHUNKS;
        #pragma unroll
        for (int k = 0; k < 6; ++k) {
            int j = tid + k * THREADS;
            if (j < CHUNKS) r[k] = g[j];
        }
    }

    compute_tile(s_tile, tab, lane, wavei);
    __syncthreads();

    {   // writeback tile A (stores overlap tile-B loads in the VMEM queue)
        float4* g = out4 + (size_t)bid * CHUNKS;
        #pragma unroll
        for (int k = 0; k < 6; ++k) {
            int j = tid + k * THREADS;
            if (j < CHUNKS) g[j] = s4[j];
        }
    }
    __syncthreads();   // writeback ds_reads done before tile-B overwrite

    // ================= tile B =================
    #pragma unroll
    for (int k = 0; k < 6; ++k) {
        int j = tid + k * THREADS;
        if (j < CHUNKS) s4[j] = r[k];
    }
    __syncthreads();

    compute_tile(s_tile, tab, lane, wavei);
    __syncthreads();

    {
        float4* g = out4 + (size_t)(bid + NBLK) * CHUNKS;
        #pragma unroll
        for (int k = 0; k < 6; ++k) {
            int j = tid + k * THREADS;
            if (j < CHUNKS) g[j] = s4[j];
        }
    }
}

extern "C" void kernel_launch(void* const* d_in, const int* in_sizes, int n_in,
                              void* d_out, int out_size, void* d_ws, size_t ws_size,
                              hipStream_t stream)
{
    const float* x  = (const float*)d_in[0];
    const float* sa = (const float*)d_in[1];
    const float* sb = (const float*)d_in[2];
    const float* op = (const float*)d_in[3];
    float* tab = (float*)d_ws;              // 81*24*4 = 7776 B
    float* outp = (float*)d_out;

    logic_prep_kernel<<<1, 256, 0, stream>>>(sa, sb, op, tab);
    logic_main_kernel<<<NBLK, THREADS, 0, stream>>>(x, tab, outp);
}

// Round 7
// 30.653 us; speedup vs baseline: 1.3956x; 1.3956x over previous
//
#include <hip/hip_runtime.h>
#include <math.h>

// LogicConv2d, single fused kernel.
//
// Block = 256 threads (4 waves) <-> 64 batches; lane <-> batch.
//  - Waves 0-2 stage the 64x81 input tile into LDS (coalesced float4).
//  - Wave 3 concurrently builds the weight table in LDS: softmax(sel_a),
//    softmax(sel_b), and the 16-way soft-logic mix collapsed to
//    out = Cab*ab + Ca*a + Cb*b + C0.   tab[81][24] = sa[9] sb[9] C[4] pad.
//  - One barrier. Compute: wave w (w<3) owns units 27w..27w+26 == patch-row
//    w; 27 inputs hoisted to registers; weights via wave-uniform
//    ds_read_b128 (broadcast, immediate offsets); fully unrolled.
//    Read-slice == write-slice per wave -> results overwrite the tile.
//  - One barrier. Coalesced float4 writeback by all 4 waves.
//
// LDS = 20736 + 7776 = 28.5 KB -> 5 blocks/CU; grid 2048 -> 1.6 residency
// rounds (late blocks' loads overlap early blocks' stores).

#define NB      131072
#define NUNITS  81
#define BPB     64            // batches per block
#define THREADS 256
#define NBLK    (NB / BPB)    // 2048
#define REC     24            // floats per unit record (96 B, 16B-aligned)
#define CHUNKS  1296          // BPB*81/4 float4 per tile

__global__ __launch_bounds__(THREADS)
void logic_fused_kernel(const float* __restrict__ x,
                        const float* __restrict__ sa_logits,
                        const float* __restrict__ sb_logits,
                        const float* __restrict__ op_logits,
                        float* __restrict__ out)
{
    __shared__ float s_tile[BPB * 81];     // 20736 B
    __shared__ float s_tab[NUNITS * REC];  //  7776 B

    const int tid   = threadIdx.x;
    const int lane  = tid & 63;
    const int wavei = __builtin_amdgcn_readfirstlane(tid >> 6);
    const size_t b0 = (size_t)blockIdx.x * BPB;

    if (wavei < 3) {
        // ---- staging by waves 0-2: 1296 chunks / 192 threads = 7 iters ----
        const float4* gsrc = (const float4*)(x + b0 * 81);
        float4* s4 = (float4*)s_tile;
        const int t3 = wavei * 64 + lane;          // 0..191
        #pragma unroll
        for (int k = 0; k < 7; ++k) {
            int j = t3 + k * 192;
            if (j < CHUNKS) s4[j] = gsrc[j];
        }
    } else {
        // ---- wave 3: build weight table (hidden under staging latency) ----
        for (int u = lane; u < NUNITS; u += 64) {
            float v[9], m = -1e30f;
            #pragma unroll
            for (int i = 0; i < 9; ++i) { v[i] = sa_logits[u * 9 + i]; m = fmaxf(m, v[i]); }
            float s = 0.f;
            #pragma unroll
            for (int i = 0; i < 9; ++i) { v[i] = expf(v[i] - m); s += v[i]; }
            const float r = 1.f / s;
            #pragma unroll
            for (int i = 0; i < 9; ++i) s_tab[u * REC + i] = v[i] * r;
        }
        for (int u = lane; u < NUNITS; u += 64) {
            float v[9], m = -1e30f;
            #pragma unroll
            for (int i = 0; i < 9; ++i) { v[i] = sb_logits[u * 9 + i]; m = fmaxf(m, v[i]); }
            float s = 0.f;
            #pragma unroll
            for (int i = 0; i < 9; ++i) { v[i] = expf(v[i] - m); s += v[i]; }
            const float r = 1.f / s;
            #pragma unroll
            for (int i = 0; i < 9; ++i) s_tab[u * REC + 9 + i] = v[i] * r;
        }
        for (int u = lane; u < NUNITS; u += 64) {
            float v[16], m = -1e30f;
            #pragma unroll
            for (int i = 0; i < 16; ++i) { v[i] = op_logits[u * 16 + i]; m = fmaxf(m, v[i]); }
            float s = 0.f;
            #pragma unroll
            for (int i = 0; i < 16; ++i) { v[i] = expf(v[i] - m); s += v[i]; }
            const float r = 1.f / s;
            #pragma unroll
            for (int i = 0; i < 16; ++i) v[i] *= r;
            const float cab = v[1] - v[2] - v[4] - 2.f*v[6] - v[7] + v[8] + 2.f*v[9]
                            + v[11] + v[13] - v[14];
            const float ca  = v[2] + v[3] + v[6] + v[7] - v[8] - v[9] - v[12] - v[13];
            const float cb  = v[4] + v[5] + v[6] + v[7] - v[8] - v[9] - v[10] - v[11];
            const float c0  = v[8] + v[9] + v[10] + v[11] + v[12] + v[13] + v[14] + v[15];
            s_tab[u * REC + 18] = cab;
            s_tab[u * REC + 19] = ca;
            s_tab[u * REC + 20] = cb;
            s_tab[u * REC + 21] = c0;
        }
    }

    __syncthreads();

    // ---- compute: wave w (w<3) owns units 27w..27w+26 (== patch-row w) ----
    if (wavei < 3) {
        float* my = s_tile + lane * 81 + wavei * 27;   // read-slice == write-slice

        float in[27];                                   // img rows 3w..3w+2
        #pragma unroll
        for (int j = 0; j < 27; ++j) in[j] = my[j];

        const float* __restrict__ wt = s_tab + wavei * 27 * REC;  // uniform base

        #pragma unroll
        for (int j = 0; j < 27; ++j) {                  // unit u = 27*wavei + j
            const int q = j / 9;                        // patch col within row
            const float* __restrict__ wr = wt + j * REC;  // uniform ds_read, imm offs
            float a = 0.f, b = 0.f;
            #pragma unroll
            for (int i = 0; i < 9; ++i) {
                const float xi = in[q * 3 + (i / 3) * 9 + (i % 3)];
                a = fmaf(xi, wr[i],     a);
                b = fmaf(xi, wr[9 + i], b);
            }
            const float ab = a * b;
            my[j] = fmaf(wr[18], ab, fmaf(wr[19], a, fmaf(wr[20], b, wr[21])));
        }
    }

    __syncthreads();

    // ---- coalesced writeback, all 4 waves ----
    {
        const float4* s4 = (const float4*)s_tile;
        float4* gdst = (float4*)(out + b0 * 81);
        #pragma unroll
        for (int k = 0; k < 6; ++k) {
            int j = tid + k * THREADS;
            if (j < CHUNKS) gdst[j] = s4[j];
        }
    }
}

extern "C" void kernel_launch(void* const* d_in, const int* in_sizes, int n_in,
                              void* d_out, int out_size, void* d_ws, size_t ws_size,
                              hipStream_t stream)
{
    const float* x  = (const float*)d_in[0];
    const float* sa = (const float*)d_in[1];
    const float* sb = (const float*)d_in[2];
    const float* op = (const float*)d_in[3];
    float* outp = (float*)d_out;

    logic_fused_kernel<<<NBLK, THREADS, 0, stream>>>(x, sa, sb, op, outp);
}